// Round 12
// baseline (321.703 us; speedup 1.0000x reference)
//
#include <hip/hip_runtime.h>
#include <cstdint>
#include <cstddef>

namespace {

typedef short bf16x8 __attribute__((ext_vector_type(8)));
typedef float f32x4 __attribute__((ext_vector_type(4)));

constexpr int kNInv  = 100000;
constexpr int kNFund = 20000;
constexpr int kH     = 128;
constexpr int kE     = 600000;
constexpr int kEL    = 200000;

// L1 weight arena element offsets (bf16 elems)
constexpr int kW1lIF = 0;        // 128x128
constexpr int kW1rIF = 16384;    // 128x64
constexpr int kW1lFI = 24576;    // 128x64
constexpr int kW1rFI = 32768;    // 128x128
constexpr int kWTot  = 49152;

// composite (layer2 x predictor) arena: 4 x 128x128 bf16
constexpr int kCW2lFI = 0;
constexpr int kCW2rFI = 16384;
constexpr int kCW2lIF = 32768;
constexpr int kCW2rIF = 49152;

__device__ __forceinline__ float bf_lo(uint32_t u) {
  union { uint32_t i; float f; } v; v.i = u << 16; return v.f;
}
__device__ __forceinline__ float bf_hi(uint32_t u) {
  union { uint32_t i; float f; } v; v.i = u & 0xffff0000u; return v.f;
}
__device__ __forceinline__ ushort f2bf(float f) {  // round-nearest-even
  union { float f; uint32_t i; } v; v.f = f;
  uint32_t x = v.i;
  return (ushort)((x + 0x7fffu + ((x >> 16) & 1u)) >> 16);
}

// ---------- conversion sizes ----------
constexpr int kXiQ = kNInv * 128 / 4;            // 3,200,000
constexpr int kXfQ = kNFund * 64 / 4;            // 320,000
constexpr int kWQ  = kWTot / 4;                  // 36,864
constexpr int kTotQ = kXiQ + kXfQ + kWQ;         // 3,556,864 = 13894*256
constexpr int kConvB = kTotQ / 256;              // 13,894

// ---------- f32 -> bf16 conversion chunk ----------
__device__ void convert_body(int q, const float* __restrict__ xi, const float* __restrict__ xf,
                             const float* w0, const float* w1, const float* w2, const float* w3,
                             ushort* __restrict__ xi_b, ushort* __restrict__ xf_b,
                             ushort* __restrict__ wa) {
  const float* src;
  ushort* dst;
  int sidx, didx;
  if (q < kXiQ) {
    src = xi; dst = xi_b; sidx = q * 4; didx = q * 4;
  } else if (q < kXiQ + kXfQ) {
    src = xf; dst = xf_b; sidx = (q - kXiQ) * 4; didx = sidx;
  } else {
    const int e = (q - kXiQ - kXfQ) * 4;
    const float* ws[4] = {w0, w1, w2, w3};
    const int beg[5] = {kW1lIF, kW1rIF, kW1lFI, kW1rFI, kWTot};
    int s = 0;
    while (e >= beg[s + 1]) ++s;
    src = ws[s]; dst = wa; sidx = e - beg[s]; didx = e;
  }
  float4 v = *(const float4*)(src + sidx);
  ushort4 o = make_ushort4(f2bf(v.x), f2bf(v.y), f2bf(v.z), f2bf(v.w));
  *(ushort4*)(dst + didx) = o;
}

// ---------- composite weights: cW = Wp_half @ W2 (f32 math, bf16 out) ----------
__device__ void composite_body(int b, const float* __restrict__ Wp1,
                               const float* __restrict__ W2l_fi, const float* __restrict__ W2r_fi,
                               const float* __restrict__ W2l_if, const float* __restrict__ W2r_if,
                               const float* __restrict__ b2_fi, const float* __restrict__ b2_if,
                               const float* __restrict__ bp1,
                               ushort* __restrict__ cw, float* __restrict__ bu_inv,
                               float* __restrict__ bu_fund, float* sA /* [32*132] */) {
  const int tid = threadIdx.x;
  if (b == 16) {
    if (tid < 128) {
      float s = 0.f;
      for (int j = 0; j < 128; ++j) s += Wp1[(size_t)tid * 256 + j] * b2_fi[j];
      bu_inv[tid] = s;
    } else {
      const int o = tid - 128;
      float s = bp1[o];
      for (int j = 0; j < 128; ++j) s += Wp1[(size_t)o * 256 + 128 + j] * b2_if[j];
      bu_fund[o] = s;
    }
    return;
  }
  const int m = b >> 2;
  const int rb = (b & 3) * 32;
  const float* A = Wp1 + (m >= 2 ? 128 : 0);
  const float* B = (m == 0) ? W2l_fi : (m == 1) ? W2r_fi : (m == 2) ? W2l_if : W2r_if;
  for (int i = tid; i < 32 * 128; i += 256) {
    const int r = i >> 7, c = i & 127;
    sA[r * 132 + c] = A[(size_t)(rb + r) * 256 + c];
  }
  __syncthreads();
  const int lr = tid >> 3;
  const int k0 = (tid & 7) * 16;
  float acc[16];
#pragma unroll
  for (int i = 0; i < 16; ++i) acc[i] = 0.f;
  for (int j = 0; j < 128; ++j) {
    const float a = sA[lr * 132 + j];
    const float* Brow = B + (size_t)j * 128 + k0;
#pragma unroll
    for (int i = 0; i < 16; i += 4) {
      float4 v = *(const float4*)(Brow + i);
      acc[i] += a * v.x; acc[i + 1] += a * v.y; acc[i + 2] += a * v.z; acc[i + 3] += a * v.w;
    }
  }
  ushort* dst = cw + (size_t)m * 16384 + (size_t)(rb + lr) * 128 + k0;
  ushort ov[16];
#pragma unroll
  for (int i = 0; i < 16; ++i) ov[i] = f2bf(acc[i]);
#pragma unroll
  for (int i = 0; i < 16; i += 4)
    *(ushort4*)(dst + i) = *(const ushort4*)(ov + i);
}

// ---------- prep: [convert][composite] (count kept separate: atomics contend) ----------
__global__ __launch_bounds__(256) void prep(
    const float* xi, const float* xf,
    const float* w0, const float* w1, const float* w2, const float* w3,
    ushort* xi_b, ushort* xf_b, ushort* wa,
    const float* Wp1, const float* W2l_fi, const float* W2r_fi,
    const float* W2l_if, const float* W2r_if,
    const float* b2_fi, const float* b2_if, const float* bp1,
    ushort* cw, float* bu_inv, float* bu_fund) {
  __shared__ float smem[32 * 132];
  const int b = blockIdx.x;
  if (b < kConvB) {
    convert_body(b * 256 + threadIdx.x, xi, xf, w0, w1, w2, w3, xi_b, xf_b, wa);
  } else {
    composite_body(b - kConvB, Wp1, W2l_fi, W2r_fi, W2l_if, W2r_if,
                   b2_fi, b2_if, bp1, cw, bu_inv, bu_fund, smem);
  }
}

// ---------- count + rank capture (atomicAdd returns rank) ----------
__global__ void count_rank2(const int* __restrict__ d0, int* __restrict__ g0,
                            int* __restrict__ r0v,
                            const int* __restrict__ d1, int* __restrict__ g1,
                            int* __restrict__ r1v, int n) {
  int e = blockIdx.x * blockDim.x + threadIdx.x;
  if (e < n) {
    r0v[e] = atomicAdd(&g0[d0[e]], 1);
  } else if (e < 2 * n) {
    int ee = e - n;
    r1v[ee] = atomicAdd(&g1[d1[ee]], 1);
  }
}

// ---------- two-level exclusive scan over deg ----------

__device__ __forceinline__ void scan_partial_body(const int* __restrict__ deg,
                                                  int* __restrict__ bsum, int n, int blk) {
  __shared__ int red[256];
  const int tid = threadIdx.x;
  const int base = blk * 1024 + tid * 4;
  int s = 0;
  if (base + 3 < n) {
    int4 v = *(const int4*)(deg + base);
    s = v.x + v.y + v.z + v.w;
  } else {
    for (int i = 0; i < 4; ++i)
      if (base + i < n) s += deg[base + i];
  }
  red[tid] = s;
  __syncthreads();
  for (int d = 128; d > 0; d >>= 1) {
    if (tid < d) red[tid] += red[tid + d];
    __syncthreads();
  }
  if (tid == 0) bsum[blk] = red[0];
}

__global__ void scan_partial2(const int* __restrict__ degF, int* __restrict__ bsumF, int nF, int nbF,
                              const int* __restrict__ degI, int* __restrict__ bsumI, int nI) {
  if ((int)blockIdx.x < nbF) scan_partial_body(degF, bsumF, nF, blockIdx.x);
  else scan_partial_body(degI, bsumI, nI, blockIdx.x - nbF);
}

// scan_apply with inline bsum prefix (bsum raw block totals; <=118 entries)
__device__ __forceinline__ void scan_apply_body(const int* __restrict__ deg,
                                                const int* __restrict__ bsum,
                                                int* __restrict__ off, int n, int blk) {
  __shared__ int red[256];
  __shared__ int sbase;
  const int tid = threadIdx.x;
  int part = 0;
  for (int i = tid; i < blk; i += 256) part += bsum[i];
  red[tid] = part;
  __syncthreads();
  for (int d = 128; d > 0; d >>= 1) {
    if (tid < d) red[tid] += red[tid + d];
    __syncthreads();
  }
  if (tid == 0) sbase = red[0];
  __syncthreads();
  const int base0 = sbase;
  __syncthreads();

  const int base = blk * 1024 + tid * 4;
  int v[4] = {0, 0, 0, 0};
  const bool full = (base + 3 < n);
  if (full) {
    int4 t = *(const int4*)(deg + base);
    v[0] = t.x; v[1] = t.y; v[2] = t.z; v[3] = t.w;
  } else {
    for (int i = 0; i < 4; ++i)
      if (base + i < n) v[i] = deg[base + i];
  }
  const int s = v[0] + v[1] + v[2] + v[3];
  red[tid] = s;
  __syncthreads();
  for (int d = 1; d < 256; d <<= 1) {
    int t = (tid >= d) ? red[tid - d] : 0;
    __syncthreads();
    red[tid] += t;
    __syncthreads();
  }
  int o[4];
  o[0] = base0 + red[tid] - s;
  o[1] = o[0] + v[0];
  o[2] = o[1] + v[1];
  o[3] = o[2] + v[2];
  if (full) {
    *(int4*)(off + base) = make_int4(o[0], o[1], o[2], o[3]);
  } else {
    for (int i = 0; i < 4; ++i)
      if (base + i < n) off[base + i] = o[i];
  }
#pragma unroll
  for (int i = 0; i < 4; ++i)
    if (base + i == n - 1) off[n] = o[i] + v[i];
}

__global__ void scan_apply2(const int* __restrict__ degF, const int* __restrict__ bsumF,
                            int* __restrict__ offF, int nF, int nbF,
                            const int* __restrict__ degI, const int* __restrict__ bsumI,
                            int* __restrict__ offI, int nI) {
  if ((int)blockIdx.x < nbF) scan_apply_body(degF, bsumF, offF, nF, blockIdx.x);
  else scan_apply_body(degI, bsumI, offI, nI, blockIdx.x - nbF);
}

// ---------- atomic-free CSR fill using captured ranks ----------
__global__ void fill2(const int* __restrict__ s0, const int* __restrict__ d0,
                      const int* __restrict__ r0v, const int* __restrict__ off0,
                      int* __restrict__ c0,
                      const int* __restrict__ s1, const int* __restrict__ d1,
                      const int* __restrict__ r1v, const int* __restrict__ off1,
                      int* __restrict__ c1, int n) {
  int e = blockIdx.x * blockDim.x + threadIdx.x;
  if (e < n) {
    c0[off0[d0[e]] + r0v[e]] = s0[e];
  } else if (e < 2 * n) {
    int ee = e - n;
    c1[off1[d1[ee]] + r1v[ee]] = s1[ee];
  }
}

// ---------- fused SAGE layer: [gather means -> LDS] + [MFMA GEMM] ----------
// Block: 256 threads, 128 output nodes. Phase 1: one GL-lane group per node,
// clamped DEP-deep gather, lane owns its 8 columns (no reduction), result to
// padded LDS tile. Phase 2: 4-wave MFMA GEMM, A1 from LDS (+8 pad -> 2-way
// aliasing = free), A2(root)+W from global (W is L2-hot, 48-64KB).

__device__ __forceinline__ void acc8w(float* a, uint4 u, float w) {
  a[0] = fmaf(w, bf_lo(u.x), a[0]); a[1] = fmaf(w, bf_hi(u.x), a[1]);
  a[2] = fmaf(w, bf_lo(u.y), a[2]); a[3] = fmaf(w, bf_hi(u.y), a[3]);
  a[4] = fmaf(w, bf_lo(u.z), a[4]); a[5] = fmaf(w, bf_hi(u.z), a[5]);
  a[6] = fmaf(w, bf_lo(u.w), a[6]); a[7] = fmaf(w, bf_hi(u.w), a[7]);
}

template <int D1, int DEPA, int D2>
__device__ void fused_layer_body(
    const ushort* __restrict__ gtab, const int* __restrict__ csr, const int* __restrict__ off,
    const ushort* __restrict__ root,
    const ushort* __restrict__ W1, const ushort* __restrict__ W2,
    const float* __restrict__ bias, int act,
    ushort* __restrict__ out, int n, int blk, ushort* lds_a) {
  constexpr int LDA = D1 + 8;
  constexpr int K1 = D1 / 32;
  constexpr int K2 = D2 / 32;
  const int tid = threadIdx.x;
  const int row0 = blk * 128;

  // ---- phase 1: gather means into LDS ----
  {
    constexpr int GL = (D1 == 128) ? 16 : 8;   // lanes per group (16B/lane)
    constexpr int NG = 256 / GL;               // groups per block
    const int grp = tid / GL;
    const int ll = tid % GL;
    const size_t co = (size_t)ll * 8;
    for (int r = grp; r < 128; r += NG) {
      const int node = min(row0 + r, n - 1);
      const int lo = off[node], hi = off[node + 1];
      float a[8] = {0.f, 0.f, 0.f, 0.f, 0.f, 0.f, 0.f, 0.f};
      for (int e0 = lo; e0 < hi; e0 += DEPA) {
        int idx[DEPA];
        float w[DEPA];
#pragma unroll
        for (int j = 0; j < DEPA; ++j) {
          const int e = e0 + j;
          idx[j] = csr[min(e, hi - 1)];
          w[j] = (e < hi) ? 1.0f : 0.0f;
        }
        uint4 u[DEPA];
#pragma unroll
        for (int j = 0; j < DEPA; ++j)
          u[j] = *(const uint4*)(gtab + (size_t)idx[j] * D1 + co);
#pragma unroll
        for (int j = 0; j < DEPA; ++j) acc8w(a, u[j], w[j]);
      }
      const float sc = (hi > lo) ? 1.0f / (float)(hi - lo) : 0.0f;
      ushort o8[8];
#pragma unroll
      for (int i = 0; i < 8; ++i) o8[i] = f2bf(a[i] * sc);
      *(uint4*)&lds_a[(size_t)r * LDA + co] = *(const uint4*)o8;
    }
  }
  __syncthreads();

  // ---- phase 2: GEMM ----
  const int wid = tid >> 6;
  const int lane = tid & 63;
  const int lo16 = lane & 15;
  const int hi4 = lane >> 4;
  const int rl0 = wid * 32 + lo16;
  const int rl1 = rl0 + 16;
  const int r0g = min(row0 + rl0, n - 1);
  const int r1g = min(row0 + rl1, n - 1);

  f32x4 acc[2][8];
#pragma unroll
  for (int rt = 0; rt < 2; ++rt)
#pragma unroll
    for (int ct = 0; ct < 8; ++ct)
      acc[rt][ct] = (f32x4){0.f, 0.f, 0.f, 0.f};

  // A1 frags from LDS
  bf16x8 aA[2][K1];
#pragma unroll
  for (int k = 0; k < K1; ++k) {
    aA[0][k] = *(const bf16x8*)&lds_a[(size_t)rl0 * LDA + k * 32 + hi4 * 8];
    aA[1][k] = *(const bf16x8*)&lds_a[(size_t)rl1 * LDA + k * 32 + hi4 * 8];
  }
  // A2 (root) frags from global
  bf16x8 aB[2][K2];
  {
    const ushort* b0p = root + (size_t)r0g * D2 + hi4 * 8;
    const ushort* b1p = root + (size_t)r1g * D2 + hi4 * 8;
#pragma unroll
    for (int k = 0; k < K2; ++k) {
      aB[0][k] = *(const bf16x8*)(b0p + k * 32);
      aB[1][k] = *(const bf16x8*)(b1p + k * 32);
    }
  }

  const ushort* wp1 = W1 + (size_t)lo16 * D1 + hi4 * 8;
#pragma unroll
  for (int k = 0; k < K1; ++k) {
#pragma unroll
    for (int ct = 0; ct < 8; ++ct) {
      bf16x8 w = *(const bf16x8*)(wp1 + (size_t)ct * 16 * D1 + k * 32);
      acc[0][ct] = __builtin_amdgcn_mfma_f32_16x16x32_bf16(w, aA[0][k], acc[0][ct], 0, 0, 0);
      acc[1][ct] = __builtin_amdgcn_mfma_f32_16x16x32_bf16(w, aA[1][k], acc[1][ct], 0, 0, 0);
    }
  }
  const ushort* wp2 = W2 + (size_t)lo16 * D2 + hi4 * 8;
#pragma unroll
  for (int k = 0; k < K2; ++k) {
#pragma unroll
    for (int ct = 0; ct < 8; ++ct) {
      bf16x8 w = *(const bf16x8*)(wp2 + (size_t)ct * 16 * D2 + k * 32);
      acc[0][ct] = __builtin_amdgcn_mfma_f32_16x16x32_bf16(w, aB[0][k], acc[0][ct], 0, 0, 0);
      acc[1][ct] = __builtin_amdgcn_mfma_f32_16x16x32_bf16(w, aB[1][k], acc[1][ct], 0, 0, 0);
    }
  }

  const int colb = hi4 * 4;
#pragma unroll
  for (int rt = 0; rt < 2; ++rt) {
    const int row = row0 + (rt ? rl1 : rl0);
    if (row < n) {
#pragma unroll
      for (int ct = 0; ct < 8; ++ct) {
        float b4[4];
        *(float4*)b4 = *(const float4*)(bias + ct * 16 + colb);
        ushort o[4];
#pragma unroll
        for (int j = 0; j < 4; ++j) {
          float x = acc[rt][ct][j] + b4[j];
          if (act) x = fmaxf(x, 0.f);
          o[j] = f2bf(x);
        }
        *(ushort4*)(out + (size_t)row * kH + ct * 16 + colb) = *(const ushort4*)o;
      }
    }
  }
}

__global__ __launch_bounds__(256) void fused_layer1(
    const ushort* xi_b, const int* csr_if, const int* off_fund, const ushort* xf_b,
    const ushort* W1lif, const ushort* W1rif, const float* b1if, ushort* outF, int nbf,
    const int* csr_fi, const int* off_inv,
    const ushort* W1lfi, const ushort* W1rfi, const float* b1fi, ushort* outI) {
  __shared__ ushort lds_a[128 * 136];
  if ((int)blockIdx.x < nbf)
    fused_layer_body<128, 8, 64>(xi_b, csr_if, off_fund, xf_b, W1lif, W1rif, b1if, 1,
                                 outF, kNFund, blockIdx.x, lds_a);
  else
    fused_layer_body<64, 4, 128>(xf_b, csr_fi, off_inv, xi_b, W1lfi, W1rfi, b1fi, 1,
                                 outI, kNInv, blockIdx.x - nbf, lds_a);
}

__global__ __launch_bounds__(256) void fused_layer2(
    const ushort* hinv, const int* csr_if, const int* off_fund, const ushort* hfund,
    const ushort* cWlif, const ushort* cWrif, const float* buF, ushort* outF, int nbf,
    const int* csr_fi, const int* off_inv,
    const ushort* cWlfi, const ushort* cWrfi, const float* buI, ushort* outI) {
  __shared__ ushort lds_a[128 * 136];
  if ((int)blockIdx.x < nbf)
    fused_layer_body<128, 8, 128>(hinv, csr_if, off_fund, hfund, cWlif, cWrif, buF, 0,
                                  outF, kNFund, blockIdx.x, lds_a);
  else
    fused_layer_body<128, 4, 128>(hfund, csr_fi, off_inv, hinv, cWlfi, cWrfi, buI, 0,
                                  outI, kNInv, blockIdx.x - nbf, lds_a);
}

// ---------- link predictor: 4 links per wave (16-lane quads, 16B/lane) ----------

__global__ void link_pred(const ushort* __restrict__ u_inv, const ushort* __restrict__ u_fund,
                          const int* __restrict__ ei, const int* __restrict__ ej,
                          const float* __restrict__ Wp2, const float* __restrict__ bp2,
                          float* __restrict__ out, int nl) {
  const int wave = (int)((blockIdx.x * blockDim.x + threadIdx.x) >> 6);
  const int lane = threadIdx.x & 63;
  const int q = lane >> 4, l16 = lane & 15;
  const int link = wave * 4 + q;
  if (link >= nl) return;
  const int i = ei[link];
  const int j = ej[link];
  uint4 ua = *(const uint4*)(u_inv + (size_t)i * 128 + l16 * 8);
  uint4 ub = *(const uint4*)(u_fund + (size_t)j * 128 + l16 * 8);
  float4 w0 = *(const float4*)(Wp2 + l16 * 8);
  float4 w1 = *(const float4*)(Wp2 + l16 * 8 + 4);
  float p = fmaxf(bf_lo(ua.x) + bf_lo(ub.x), 0.f) * w0.x
          + fmaxf(bf_hi(ua.x) + bf_hi(ub.x), 0.f) * w0.y
          + fmaxf(bf_lo(ua.y) + bf_lo(ub.y), 0.f) * w0.z
          + fmaxf(bf_hi(ua.y) + bf_hi(ub.y), 0.f) * w0.w
          + fmaxf(bf_lo(ua.z) + bf_lo(ub.z), 0.f) * w1.x
          + fmaxf(bf_hi(ua.z) + bf_hi(ub.z), 0.f) * w1.y
          + fmaxf(bf_lo(ua.w) + bf_lo(ub.w), 0.f) * w1.z
          + fmaxf(bf_hi(ua.w) + bf_hi(ub.w), 0.f) * w1.w;
#pragma unroll
  for (int o = 8; o > 0; o >>= 1) p += __shfl_xor(p, o);
  if (l16 == 0) out[link] = 1.0f / (1.0f + expf(-(p + bp2[0])));
}

}  // namespace

extern "C" void kernel_launch(void* const* d_in, const int* in_sizes, int n_in,
                              void* d_out, int out_size, void* d_ws, size_t ws_size,
                              hipStream_t stream) {
  const float* x_inv  = (const float*)d_in[0];
  const float* x_fund = (const float*)d_in[1];
  const int* src_if   = (const int*)d_in[2];
  const int* dst_if   = (const int*)d_in[3];
  const int* src_fi   = (const int*)d_in[4];
  const int* dst_fi   = (const int*)d_in[5];
  const int* eli_inv  = (const int*)d_in[6];
  const int* eli_fund = (const int*)d_in[7];
  const float* W1l_if = (const float*)d_in[8];
  const float* b1_if  = (const float*)d_in[9];
  const float* W1r_if = (const float*)d_in[10];
  const float* W1l_fi = (const float*)d_in[11];
  const float* b1_fi  = (const float*)d_in[12];
  const float* W1r_fi = (const float*)d_in[13];
  const float* W2l_if = (const float*)d_in[14];
  const float* b2_if  = (const float*)d_in[15];
  const float* W2r_if = (const float*)d_in[16];
  const float* W2l_fi = (const float*)d_in[17];
  const float* b2_fi  = (const float*)d_in[18];
  const float* W2r_fi = (const float*)d_in[19];
  const float* Wp1    = (const float*)d_in[20];
  const float* bp1    = (const float*)d_in[21];
  const float* Wp2    = (const float*)d_in[22];
  const float* bp2    = (const float*)d_in[23];
  float* out = (float*)d_out;

  char* p = (char*)d_ws;
  auto alloc = [&](size_t bytes) -> void* {
    void* r = (void*)p;
    p += (bytes + 255) & ~(size_t)255;
    return r;
  };
  int* deg_fund = (int*)alloc((size_t)kNFund * 4);
  int* deg_inv  = (int*)alloc((size_t)kNInv * 4);
  int* off_fund = (int*)alloc((size_t)(kNFund + 1) * 4);
  int* off_inv  = (int*)alloc((size_t)(kNInv + 1) * 4);
  int* bsumF    = (int*)alloc((size_t)1024 * 4);
  int* bsumI    = (int*)alloc((size_t)1024 * 4);
  int* rank_if  = (int*)alloc((size_t)kE * 4);
  int* rank_fi  = (int*)alloc((size_t)kE * 4);
  int* csr_if   = (int*)alloc((size_t)kE * 4);
  int* csr_fi   = (int*)alloc((size_t)kE * 4);
  ushort* xi_b = (ushort*)alloc((size_t)kNInv * 128 * 2);
  ushort* xf_b = (ushort*)alloc((size_t)kNFund * 64 * 2);
  ushort* wa   = (ushort*)alloc((size_t)kWTot * 2);
  ushort* cw   = (ushort*)alloc((size_t)4 * 16384 * 2);
  float* bu_inv  = (float*)alloc((size_t)128 * 4);
  float* bu_fund = (float*)alloc((size_t)128 * 4);
  ushort* bufB = (ushort*)alloc((size_t)kNFund * 128 * 2);  // h_fund
  ushort* bufD = (ushort*)alloc((size_t)kNInv * 128 * 2);   // h_inv
  ushort* bufE = (ushort*)alloc((size_t)kNFund * 128 * 2);  // u_fund
  ushort* bufF = (ushort*)alloc((size_t)kNInv * 128 * 2);   // u_inv

  const int TB = 256;
  const int nbFund = (kNFund + 1023) / 1024;  // 20
  const int nbInv  = (kNInv + 1023) / 1024;   // 98
  const int gemmF = (kNFund + 127) / 128;     // 157
  const int gemmI = (kNInv + 127) / 128;      // 782

  // 0) zero degree counters
  hipMemsetAsync(deg_fund, 0, (size_t)kNFund * 4, stream);
  hipMemsetAsync(deg_inv, 0, (size_t)kNInv * 4, stream);

  // 1) prep: bf16 convert + composite weights (streaming only)
  prep<<<kConvB + 17, 256, 0, stream>>>(
      x_inv, x_fund, W1l_if, W1r_if, W1l_fi, W1r_fi, xi_b, xf_b, wa,
      Wp1, W2l_fi, W2r_fi, W2l_if, W2r_if, b2_fi, b2_if, bp1, cw, bu_inv, bu_fund);

  // 2) count + rank capture (atomics, separate: contend with streaming)
  count_rank2<<<(2 * kE + TB - 1) / TB, TB, 0, stream>>>(
      dst_if, deg_fund, rank_if, dst_fi, deg_inv, rank_fi, kE);

  // 3) scan
  scan_partial2<<<nbFund + nbInv, 256, 0, stream>>>(deg_fund, bsumF, kNFund, nbFund,
                                                    deg_inv, bsumI, kNInv);
  scan_apply2<<<nbFund + nbInv, 256, 0, stream>>>(deg_fund, bsumF, off_fund, kNFund, nbFund,
                                                  deg_inv, bsumI, off_inv, kNInv);

  // 4) atomic-free fill
  fill2<<<(2 * kE + TB - 1) / TB, TB, 0, stream>>>(
      src_if, dst_if, rank_if, off_fund, csr_if,
      src_fi, dst_fi, rank_fi, off_inv, csr_fi, kE);

  // 5) fused layer 1 (gather means -> LDS -> MFMA)
  fused_layer1<<<gemmF + gemmI, 256, 0, stream>>>(
      xi_b, csr_if, off_fund, xf_b, wa + kW1lIF, wa + kW1rIF, b1_if, bufB, gemmF,
      csr_fi, off_inv, wa + kW1lFI, wa + kW1rFI, b1_fi, bufD);

  // 6) fused layer 2 (composite weights fold in the predictor precompute)
  fused_layer2<<<gemmF + gemmI, 256, 0, stream>>>(
      bufD, csr_if, off_fund, bufB, cw + kCW2lIF, cw + kCW2rIF, bu_fund, bufE, gemmF,
      csr_fi, off_inv, cw + kCW2lFI, cw + kCW2rFI, bu_inv, bufF);

  // 7) per-link
  link_pred<<<(kEL / 4 + 3) / 4, 256, 0, stream>>>(bufF, bufE, eli_inv, eli_fund,
                                                   Wp2, bp2, out, kEL);
}

// Round 13
// 299.349 us; speedup vs baseline: 1.0747x; 1.0747x over previous
//
#include <hip/hip_runtime.h>
#include <cstdint>
#include <cstddef>

namespace {

typedef short bf16x8 __attribute__((ext_vector_type(8)));
typedef float f32x4 __attribute__((ext_vector_type(4)));

constexpr int kNInv  = 100000;
constexpr int kNFund = 20000;
constexpr int kH     = 128;
constexpr int kE     = 600000;
constexpr int kEL    = 200000;

// L1 weight arena element offsets (bf16 elems)
constexpr int kW1lIF = 0;        // 128x128
constexpr int kW1rIF = 16384;    // 128x64
constexpr int kW1lFI = 24576;    // 128x64
constexpr int kW1rFI = 32768;    // 128x128
constexpr int kWTot  = 49152;

// composite (layer2 x predictor) arena: 4 x 128x128 bf16
constexpr int kCW2lFI = 0;
constexpr int kCW2rFI = 16384;
constexpr int kCW2lIF = 32768;
constexpr int kCW2rIF = 49152;

__device__ __forceinline__ float bf_lo(uint32_t u) {
  union { uint32_t i; float f; } v; v.i = u << 16; return v.f;
}
__device__ __forceinline__ float bf_hi(uint32_t u) {
  union { uint32_t i; float f; } v; v.i = u & 0xffff0000u; return v.f;
}
__device__ __forceinline__ ushort f2bf(float f) {  // round-nearest-even
  union { float f; uint32_t i; } v; v.f = f;
  uint32_t x = v.i;
  return (ushort)((x + 0x7fffu + ((x >> 16) & 1u)) >> 16);
}

// ---------- conversion / zero sizes (quad = float4/ushort4 of 4 elems) ----------
constexpr int kXiQ = kNInv * 128 / 4;            // 3,200,000 quads
constexpr int kXfQ = kNFund * 64 / 4;            // 320,000
constexpr int kWQ  = kWTot / 4;                  // 36,864
constexpr int kTotQ = kXiQ + kXfQ + kWQ;         // 3,556,864 (div by 4)
constexpr int kQT  = kTotQ / 4;                  // 889,216 convert threads (4 quads each)
constexpr int kZF4 = kNFund / 4;                 // 5,000 int4 zero chunks (fund)
constexpr int kZ4  = (kNFund + kNInv) / 16;      // 7,500 zero threads (4 int4 each)
constexpr int kPrepT = kQT + kZ4;
constexpr int kPrepB = (kPrepT + 255) / 256;

// ---------- f32 -> bf16 conversion, 4 quads (64B) per thread + deg zeroing ----------
__device__ void convert_body(int t, const float* __restrict__ xi, const float* __restrict__ xf,
                             const float* w0, const float* w1, const float* w2, const float* w3,
                             ushort* __restrict__ xi_b, ushort* __restrict__ xf_b,
                             ushort* __restrict__ wa,
                             int* __restrict__ deg_fund, int* __restrict__ deg_inv) {
  if (t >= kQT) {
    const int g = t - kQT;
    if (g >= kZ4) return;
    int z = g * 4;
#pragma unroll
    for (int j = 0; j < 4; ++j, ++z) {
      if (z < kZF4) ((int4*)deg_fund)[z] = make_int4(0, 0, 0, 0);
      else ((int4*)deg_inv)[z - kZF4] = make_int4(0, 0, 0, 0);
    }
    return;
  }
  const int q0 = t * 4;
  const float* src;
  ushort* dst;
  int sq, dq;  // quad indices
  if (q0 < kXiQ) {
    src = xi; dst = xi_b; sq = q0; dq = q0;
  } else if (q0 < kXiQ + kXfQ) {
    src = xf; dst = xf_b; sq = q0 - kXiQ; dq = sq;
  } else {
    const int e = (q0 - kXiQ - kXfQ) * 4;  // elem offset into arena
    const float* ws[4] = {w0, w1, w2, w3};
    const int beg[5] = {kW1lIF, kW1rIF, kW1lFI, kW1rFI, kWTot};
    int s = 0;
    while (e >= beg[s + 1]) ++s;
    src = ws[s]; dst = wa; sq = (e - beg[s]) / 4; dq = e / 4;
  }
#pragma unroll
  for (int j = 0; j < 4; ++j) {
    float4 v = ((const float4*)src)[sq + j];
    ushort4 o = make_ushort4(f2bf(v.x), f2bf(v.y), f2bf(v.z), f2bf(v.w));
    ((ushort4*)dst)[dq + j] = o;
  }
}

// ---------- composite weights: cW = Wp_half @ W2 (f32 math, bf16 out) ----------
__device__ void composite_body(int b, const float* __restrict__ Wp1,
                               const float* __restrict__ W2l_fi, const float* __restrict__ W2r_fi,
                               const float* __restrict__ W2l_if, const float* __restrict__ W2r_if,
                               const float* __restrict__ b2_fi, const float* __restrict__ b2_if,
                               const float* __restrict__ bp1,
                               ushort* __restrict__ cw, float* __restrict__ bu_inv,
                               float* __restrict__ bu_fund, float* sA /* [32*132] */) {
  const int tid = threadIdx.x;
  if (b == 16) {
    if (tid < 128) {
      float s = 0.f;
      for (int j = 0; j < 128; ++j) s += Wp1[(size_t)tid * 256 + j] * b2_fi[j];
      bu_inv[tid] = s;
    } else {
      const int o = tid - 128;
      float s = bp1[o];
      for (int j = 0; j < 128; ++j) s += Wp1[(size_t)o * 256 + 128 + j] * b2_if[j];
      bu_fund[o] = s;
    }
    return;
  }
  const int m = b >> 2;
  const int rb = (b & 3) * 32;
  const float* A = Wp1 + (m >= 2 ? 128 : 0);
  const float* B = (m == 0) ? W2l_fi : (m == 1) ? W2r_fi : (m == 2) ? W2l_if : W2r_if;
  for (int i = tid; i < 32 * 128; i += 256) {
    const int r = i >> 7, c = i & 127;
    sA[r * 132 + c] = A[(size_t)(rb + r) * 256 + c];
  }
  __syncthreads();
  const int lr = tid >> 3;
  const int k0 = (tid & 7) * 16;
  float acc[16];
#pragma unroll
  for (int i = 0; i < 16; ++i) acc[i] = 0.f;
  for (int j = 0; j < 128; ++j) {
    const float a = sA[lr * 132 + j];
    const float* Brow = B + (size_t)j * 128 + k0;
#pragma unroll
    for (int i = 0; i < 16; i += 4) {
      float4 v = *(const float4*)(Brow + i);
      acc[i] += a * v.x; acc[i + 1] += a * v.y; acc[i + 2] += a * v.z; acc[i + 3] += a * v.w;
    }
  }
  ushort* dst = cw + (size_t)m * 16384 + (size_t)(rb + lr) * 128 + k0;
  ushort ov[16];
#pragma unroll
  for (int i = 0; i < 16; ++i) ov[i] = f2bf(acc[i]);
#pragma unroll
  for (int i = 0; i < 16; i += 4)
    *(ushort4*)(dst + i) = *(const ushort4*)(ov + i);
}

// ---------- fused prep: [convert + deg-zero][composite] ----------
__global__ __launch_bounds__(256) void prep(
    const float* xi, const float* xf,
    const float* w0, const float* w1, const float* w2, const float* w3,
    ushort* xi_b, ushort* xf_b, ushort* wa,
    int* deg_fund, int* deg_inv,
    const float* Wp1, const float* W2l_fi, const float* W2r_fi,
    const float* W2l_if, const float* W2r_if,
    const float* b2_fi, const float* b2_if, const float* bp1,
    ushort* cw, float* bu_inv, float* bu_fund) {
  __shared__ float smem[32 * 132];
  const int b = blockIdx.x;
  if (b < kPrepB) {
    convert_body(b * 256 + threadIdx.x, xi, xf, w0, w1, w2, w3, xi_b, xf_b, wa,
                 deg_fund, deg_inv);
  } else {
    composite_body(b - kPrepB, Wp1, W2l_fi, W2r_fi, W2l_if, W2r_if,
                   b2_fi, b2_if, bp1, cw, bu_inv, bu_fund, smem);
  }
}

// ---------- count + rank capture: int4 dst loads, 4 atomics/thread ----------
__global__ void count_rank2(const int* __restrict__ d0, int* __restrict__ g0,
                            int* __restrict__ r0v,
                            const int* __restrict__ d1, int* __restrict__ g1,
                            int* __restrict__ r1v, int n4) {
  const int t = blockIdx.x * blockDim.x + threadIdx.x;
  if (t < n4) {
    int4 d = ((const int4*)d0)[t];
    const int e = t * 4;
    r0v[e]     = atomicAdd(&g0[d.x], 1);
    r0v[e + 1] = atomicAdd(&g0[d.y], 1);
    r0v[e + 2] = atomicAdd(&g0[d.z], 1);
    r0v[e + 3] = atomicAdd(&g0[d.w], 1);
  } else if (t < 2 * n4) {
    const int tt = t - n4;
    int4 d = ((const int4*)d1)[tt];
    const int e = tt * 4;
    r1v[e]     = atomicAdd(&g1[d.x], 1);
    r1v[e + 1] = atomicAdd(&g1[d.y], 1);
    r1v[e + 2] = atomicAdd(&g1[d.z], 1);
    r1v[e + 3] = atomicAdd(&g1[d.w], 1);
  }
}

// ---------- two-level exclusive scan over deg ----------

__device__ __forceinline__ void scan_partial_body(const int* __restrict__ deg,
                                                  int* __restrict__ bsum, int n, int blk) {
  __shared__ int red[256];
  const int tid = threadIdx.x;
  const int base = blk * 1024 + tid * 4;
  int s = 0;
  if (base + 3 < n) {
    int4 v = *(const int4*)(deg + base);
    s = v.x + v.y + v.z + v.w;
  } else {
    for (int i = 0; i < 4; ++i)
      if (base + i < n) s += deg[base + i];
  }
  red[tid] = s;
  __syncthreads();
  for (int d = 128; d > 0; d >>= 1) {
    if (tid < d) red[tid] += red[tid + d];
    __syncthreads();
  }
  if (tid == 0) bsum[blk] = red[0];
}

__global__ void scan_partial2(const int* __restrict__ degF, int* __restrict__ bsumF, int nF, int nbF,
                              const int* __restrict__ degI, int* __restrict__ bsumI, int nI) {
  if ((int)blockIdx.x < nbF) scan_partial_body(degF, bsumF, nF, blockIdx.x);
  else scan_partial_body(degI, bsumI, nI, blockIdx.x - nbF);
}

// scan_apply with inline bsum prefix (bsum raw block totals; <=118 entries)
__device__ __forceinline__ void scan_apply_body(const int* __restrict__ deg,
                                                const int* __restrict__ bsum,
                                                int* __restrict__ off, int n, int blk) {
  __shared__ int red[256];
  __shared__ int sbase;
  const int tid = threadIdx.x;
  int part = 0;
  for (int i = tid; i < blk; i += 256) part += bsum[i];
  red[tid] = part;
  __syncthreads();
  for (int d = 128; d > 0; d >>= 1) {
    if (tid < d) red[tid] += red[tid + d];
    __syncthreads();
  }
  if (tid == 0) sbase = red[0];
  __syncthreads();
  const int base0 = sbase;
  __syncthreads();

  const int base = blk * 1024 + tid * 4;
  int v[4] = {0, 0, 0, 0};
  const bool full = (base + 3 < n);
  if (full) {
    int4 t = *(const int4*)(deg + base);
    v[0] = t.x; v[1] = t.y; v[2] = t.z; v[3] = t.w;
  } else {
    for (int i = 0; i < 4; ++i)
      if (base + i < n) v[i] = deg[base + i];
  }
  const int s = v[0] + v[1] + v[2] + v[3];
  red[tid] = s;
  __syncthreads();
  for (int d = 1; d < 256; d <<= 1) {
    int t = (tid >= d) ? red[tid - d] : 0;
    __syncthreads();
    red[tid] += t;
    __syncthreads();
  }
  int o[4];
  o[0] = base0 + red[tid] - s;
  o[1] = o[0] + v[0];
  o[2] = o[1] + v[1];
  o[3] = o[2] + v[2];
  if (full) {
    *(int4*)(off + base) = make_int4(o[0], o[1], o[2], o[3]);
  } else {
    for (int i = 0; i < 4; ++i)
      if (base + i < n) off[base + i] = o[i];
  }
#pragma unroll
  for (int i = 0; i < 4; ++i)
    if (base + i == n - 1) off[n] = o[i] + v[i];
}

__global__ void scan_apply2(const int* __restrict__ degF, const int* __restrict__ bsumF,
                            int* __restrict__ offF, int nF, int nbF,
                            const int* __restrict__ degI, const int* __restrict__ bsumI,
                            int* __restrict__ offI, int nI) {
  if ((int)blockIdx.x < nbF) scan_apply_body(degF, bsumF, offF, nF, blockIdx.x);
  else scan_apply_body(degI, bsumI, offI, nI, blockIdx.x - nbF);
}

// ---------- atomic-free CSR fill using captured ranks ----------
__global__ void fill2(const int* __restrict__ s0, const int* __restrict__ d0,
                      const int* __restrict__ r0v, const int* __restrict__ off0,
                      int* __restrict__ c0,
                      const int* __restrict__ s1, const int* __restrict__ d1,
                      const int* __restrict__ r1v, const int* __restrict__ off1,
                      int* __restrict__ c1, int n) {
  int e = blockIdx.x * blockDim.x + threadIdx.x;
  if (e < n) {
    c0[off0[d0[e]] + r0v[e]] = s0[e];
  } else if (e < 2 * n) {
    int ee = e - n;
    c1[off1[d1[ee]] + r1v[ee]] = s1[ee];
  }
}

// ---------- mean aggregation: clamped 4/2-deep, subgroup decomposition ----------

__device__ __forceinline__ void acc8w(float* a, uint4 u, float w) {
  a[0] = fmaf(w, bf_lo(u.x), a[0]); a[1] = fmaf(w, bf_hi(u.x), a[1]);
  a[2] = fmaf(w, bf_lo(u.y), a[2]); a[3] = fmaf(w, bf_hi(u.y), a[3]);
  a[4] = fmaf(w, bf_lo(u.z), a[4]); a[5] = fmaf(w, bf_hi(u.z), a[5]);
  a[6] = fmaf(w, bf_lo(u.w), a[6]); a[7] = fmaf(w, bf_hi(u.w), a[7]);
}

template <int D, int DEP>
__device__ __forceinline__ void mean_node(const ushort* __restrict__ xsrc,
                                          const int* __restrict__ csr,
                                          const int* __restrict__ off,
                                          ushort* __restrict__ mean, int node, int lane) {
  constexpr int NSUB = (D == 128) ? 4 : 8;
  const int sub = (D == 128) ? (lane >> 4) : (lane >> 3);
  const int ll  = (D == 128) ? (lane & 15) : (lane & 7);
  const size_t co = (size_t)ll * 8;
  const int lo = off[node], hi = off[node + 1];
  float a[8] = {0.f, 0.f, 0.f, 0.f, 0.f, 0.f, 0.f, 0.f};
  for (int e0 = lo + sub; e0 < hi; e0 += NSUB * DEP) {
    int idx[DEP];
    float w[DEP];
#pragma unroll
    for (int j = 0; j < DEP; ++j) {
      const int e = e0 + NSUB * j;
      idx[j] = csr[min(e, hi - 1)];
      w[j] = (e < hi) ? 1.0f : 0.0f;
    }
    uint4 u[DEP];
#pragma unroll
    for (int j = 0; j < DEP; ++j)
      u[j] = *(const uint4*)(xsrc + (size_t)idx[j] * D + co);
#pragma unroll
    for (int j = 0; j < DEP; ++j) acc8w(a, u[j], w[j]);
  }
#pragma unroll
  for (int i = 0; i < 8; ++i) {
    if (D == 64) a[i] += __shfl_xor(a[i], 8);
    a[i] += __shfl_xor(a[i], 16);
    a[i] += __shfl_xor(a[i], 32);
  }
  if (sub == 0) {
    const float sc = (hi > lo) ? 1.0f / (float)(hi - lo) : 0.0f;
    ushort o8[8];
#pragma unroll
    for (int i = 0; i < 8; ++i) o8[i] = f2bf(a[i] * sc);
    *(uint4*)(mean + (size_t)node * D + co) = *(const uint4*)o8;
  }
}

template <int DA, int DEPA, int DB, int DEPB>
__global__ void sage_mean_dual(const ushort* __restrict__ xA, const int* __restrict__ csrA,
                               const int* __restrict__ offA, ushort* __restrict__ outA, int nA,
                               const ushort* __restrict__ xB, const int* __restrict__ csrB,
                               const int* __restrict__ offB, ushort* __restrict__ outB, int nB) {
  const int wave = (int)((blockIdx.x * blockDim.x + threadIdx.x) >> 6);
  const int lane = threadIdx.x & 63;
  if (wave < nA) mean_node<DA, DEPA>(xA, csrA, offA, outA, wave, lane);
  else if (wave < nA + nB) mean_node<DB, DEPB>(xB, csrB, offB, outB, wave - nA, lane);
}

// ---------- MFMA GEMM body: out[n,128] = act(A1@W1^T + A2@W2^T + bias) ----------

template <int D1, int D2>
__device__ void gemm_body(const ushort* __restrict__ A1, const ushort* __restrict__ A2,
                          const ushort* __restrict__ W1, const ushort* __restrict__ W2,
                          const float* __restrict__ bias, int act,
                          ushort* __restrict__ out, int n, int blk, ushort* lds) {
  constexpr int K1 = D1 / 32;
  constexpr int K2 = D2 / 32;
  constexpr int CH1 = 128 * D1 / 8;
  constexpr int CHT = 128 * (D1 + D2) / 8;

  const int tid = threadIdx.x;
  const int wid = tid >> 6;
  const int lane = tid & 63;
  const int lo16 = lane & 15;
  const int hi4 = lane >> 4;
  const int row0 = blk * 128 + wid * 32;

  const int r0 = min(row0 + lo16, n - 1);
  const int r1 = min(row0 + 16 + lo16, n - 1);

  bf16x8 aA[2][K1], aB[2][K2];
  {
    const ushort* a0p = A1 + (size_t)r0 * D1 + hi4 * 8;
    const ushort* a1p = A1 + (size_t)r1 * D1 + hi4 * 8;
#pragma unroll
    for (int k = 0; k < K1; ++k) {
      aA[0][k] = *(const bf16x8*)(a0p + k * 32);
      aA[1][k] = *(const bf16x8*)(a1p + k * 32);
    }
    const ushort* b0p = A2 + (size_t)r0 * D2 + hi4 * 8;
    const ushort* b1p = A2 + (size_t)r1 * D2 + hi4 * 8;
#pragma unroll
    for (int k = 0; k < K2; ++k) {
      aB[0][k] = *(const bf16x8*)(b0p + k * 32);
      aB[1][k] = *(const bf16x8*)(b1p + k * 32);
    }
  }

#pragma unroll
  for (int it = 0; it < CHT / 256; ++it) {
    const int c = it * 256 + tid;
    const int g = c * 8;
    bf16x8 v;
    int dest;
    if (g < 128 * D1) {
      const int row = g / D1, col = g % D1;
      v = *(const bf16x8*)(W1 + g);
      dest = ((col >> 5) * 8 + (row >> 4)) * 64 + (((col >> 3) & 3) << 4) + (row & 15);
    } else {
      const int g2 = g - 128 * D1;
      const int row = g2 / D2, col = g2 % D2;
      v = *(const bf16x8*)(W2 + g2);
      dest = CH1 + ((col >> 5) * 8 + (row >> 4)) * 64 + (((col >> 3) & 3) << 4) + (row & 15);
    }
    *((bf16x8*)lds + dest) = v;
  }
  __syncthreads();

  f32x4 acc[2][8];
#pragma unroll
  for (int rt = 0; rt < 2; ++rt)
#pragma unroll
    for (int ct = 0; ct < 8; ++ct)
      acc[rt][ct] = (f32x4){0.f, 0.f, 0.f, 0.f};

  const bf16x8* fr = (const bf16x8*)lds;
#pragma unroll
  for (int k = 0; k < K1; ++k) {
#pragma unroll
    for (int ct = 0; ct < 8; ++ct) {
      bf16x8 w = fr[(k * 8 + ct) * 64 + lane];
      acc[0][ct] = __builtin_amdgcn_mfma_f32_16x16x32_bf16(w, aA[0][k], acc[0][ct], 0, 0, 0);
      acc[1][ct] = __builtin_amdgcn_mfma_f32_16x16x32_bf16(w, aA[1][k], acc[1][ct], 0, 0, 0);
    }
  }
#pragma unroll
  for (int k = 0; k < K2; ++k) {
#pragma unroll
    for (int ct = 0; ct < 8; ++ct) {
      bf16x8 w = fr[CH1 + (k * 8 + ct) * 64 + lane];
      acc[0][ct] = __builtin_amdgcn_mfma_f32_16x16x32_bf16(w, aB[0][k], acc[0][ct], 0, 0, 0);
      acc[1][ct] = __builtin_amdgcn_mfma_f32_16x16x32_bf16(w, aB[1][k], acc[1][ct], 0, 0, 0);
    }
  }

  const int colb = hi4 * 4;
#pragma unroll
  for (int rt = 0; rt < 2; ++rt) {
    const int row = row0 + rt * 16 + lo16;
    if (row < n) {
#pragma unroll
      for (int ct = 0; ct < 8; ++ct) {
        float b4[4];
        *(float4*)b4 = *(const float4*)(bias + ct * 16 + colb);
        ushort o[4];
#pragma unroll
        for (int j = 0; j < 4; ++j) {
          float x = acc[rt][ct][j] + b4[j];
          if (act) x = fmaxf(x, 0.f);
          o[j] = f2bf(x);
        }
        *(ushort4*)(out + (size_t)row * kH + ct * 16 + colb) = *(const ushort4*)o;
      }
    }
  }
}

__global__ __launch_bounds__(256) void gemm_stage1(
    const ushort* A1f, const ushort* A2f, const ushort* W1f, const ushort* W2f,
    const float* biasf, ushort* outf, int nf, int nbf,
    const ushort* A1i, const ushort* A2i, const ushort* W1i, const ushort* W2i,
    const float* biasi, ushort* outi, int ni) {
  __shared__ ushort lds[128 * 192];
  if ((int)blockIdx.x < nbf)
    gemm_body<128, 64>(A1f, A2f, W1f, W2f, biasf, 1, outf, nf, blockIdx.x, lds);
  else
    gemm_body<64, 128>(A1i, A2i, W1i, W2i, biasi, 1, outi, ni, blockIdx.x - nbf, lds);
}

__global__ __launch_bounds__(256) void gemm_stage2(
    const ushort* A1f, const ushort* A2f, const ushort* W1f, const ushort* W2f,
    const float* biasf, ushort* outf, int nf, int nbf,
    const ushort* A1i, const ushort* A2i, const ushort* W1i, const ushort* W2i,
    const float* biasi, ushort* outi, int ni) {
  __shared__ ushort lds[128 * 256];
  if ((int)blockIdx.x < nbf)
    gemm_body<128, 128>(A1f, A2f, W1f, W2f, biasf, 0, outf, nf, blockIdx.x, lds);
  else
    gemm_body<128, 128>(A1i, A2i, W1i, W2i, biasi, 0, outi, ni, blockIdx.x - nbf, lds);
}

// ---------- link predictor: 4 links per wave (16-lane quads, 16B/lane) ----------

__global__ void link_pred(const ushort* __restrict__ u_inv, const ushort* __restrict__ u_fund,
                          const int* __restrict__ ei, const int* __restrict__ ej,
                          const float* __restrict__ Wp2, const float* __restrict__ bp2,
                          float* __restrict__ out, int nl) {
  const int wave = (int)((blockIdx.x * blockDim.x + threadIdx.x) >> 6);
  const int lane = threadIdx.x & 63;
  const int q = lane >> 4, l16 = lane & 15;
  const int link = wave * 4 + q;
  if (link >= nl) return;
  const int i = ei[link];
  const int j = ej[link];
  uint4 ua = *(const uint4*)(u_inv + (size_t)i * 128 + l16 * 8);
  uint4 ub = *(const uint4*)(u_fund + (size_t)j * 128 + l16 * 8);
  float4 w0 = *(const float4*)(Wp2 + l16 * 8);
  float4 w1 = *(const float4*)(Wp2 + l16 * 8 + 4);
  float p = fmaxf(bf_lo(ua.x) + bf_lo(ub.x), 0.f) * w0.x
          + fmaxf(bf_hi(ua.x) + bf_hi(ub.x), 0.f) * w0.y
          + fmaxf(bf_lo(ua.y) + bf_lo(ub.y), 0.f) * w0.z
          + fmaxf(bf_hi(ua.y) + bf_hi(ub.y), 0.f) * w0.w
          + fmaxf(bf_lo(ua.z) + bf_lo(ub.z), 0.f) * w1.x
          + fmaxf(bf_hi(ua.z) + bf_hi(ub.z), 0.f) * w1.y
          + fmaxf(bf_lo(ua.w) + bf_lo(ub.w), 0.f) * w1.z
          + fmaxf(bf_hi(ua.w) + bf_hi(ub.w), 0.f) * w1.w;
#pragma unroll
  for (int o = 8; o > 0; o >>= 1) p += __shfl_xor(p, o);
  if (l16 == 0) out[link] = 1.0f / (1.0f + expf(-(p + bp2[0])));
}

}  // namespace

extern "C" void kernel_launch(void* const* d_in, const int* in_sizes, int n_in,
                              void* d_out, int out_size, void* d_ws, size_t ws_size,
                              hipStream_t stream) {
  const float* x_inv  = (const float*)d_in[0];
  const float* x_fund = (const float*)d_in[1];
  const int* src_if   = (const int*)d_in[2];
  const int* dst_if   = (const int*)d_in[3];
  const int* src_fi   = (const int*)d_in[4];
  const int* dst_fi   = (const int*)d_in[5];
  const int* eli_inv  = (const int*)d_in[6];
  const int* eli_fund = (const int*)d_in[7];
  const float* W1l_if = (const float*)d_in[8];
  const float* b1_if  = (const float*)d_in[9];
  const float* W1r_if = (const float*)d_in[10];
  const float* W1l_fi = (const float*)d_in[11];
  const float* b1_fi  = (const float*)d_in[12];
  const float* W1r_fi = (const float*)d_in[13];
  const float* W2l_if = (const float*)d_in[14];
  const float* b2_if  = (const float*)d_in[15];
  const float* W2r_if = (const float*)d_in[16];
  const float* W2l_fi = (const float*)d_in[17];
  const float* b2_fi  = (const float*)d_in[18];
  const float* W2r_fi = (const float*)d_in[19];
  const float* Wp1    = (const float*)d_in[20];
  const float* bp1    = (const float*)d_in[21];
  const float* Wp2    = (const float*)d_in[22];
  const float* bp2    = (const float*)d_in[23];
  float* out = (float*)d_out;

  char* p = (char*)d_ws;
  auto alloc = [&](size_t bytes) -> void* {
    void* r = (void*)p;
    p += (bytes + 255) & ~(size_t)255;
    return r;
  };
  int* deg_fund = (int*)alloc((size_t)kNFund * 4);
  int* deg_inv  = (int*)alloc((size_t)kNInv * 4);
  int* off_fund = (int*)alloc((size_t)(kNFund + 1) * 4);
  int* off_inv  = (int*)alloc((size_t)(kNInv + 1) * 4);
  int* bsumF    = (int*)alloc((size_t)1024 * 4);
  int* bsumI    = (int*)alloc((size_t)1024 * 4);
  int* rank_if  = (int*)alloc((size_t)kE * 4);
  int* rank_fi  = (int*)alloc((size_t)kE * 4);
  int* csr_if   = (int*)alloc((size_t)kE * 4);
  int* csr_fi   = (int*)alloc((size_t)kE * 4);
  ushort* xi_b = (ushort*)alloc((size_t)kNInv * 128 * 2);
  ushort* xf_b = (ushort*)alloc((size_t)kNFund * 64 * 2);
  ushort* wa   = (ushort*)alloc((size_t)kWTot * 2);
  ushort* cw   = (ushort*)alloc((size_t)4 * 16384 * 2);
  float* bu_inv  = (float*)alloc((size_t)128 * 4);
  float* bu_fund = (float*)alloc((size_t)128 * 4);
  ushort* bufA = (ushort*)alloc((size_t)kNFund * 128 * 2);  // mean_fund
  ushort* bufB = (ushort*)alloc((size_t)kNFund * 128 * 2);  // h_fund
  ushort* bufC = (ushort*)alloc((size_t)kNInv * 128 * 2);   // mean_inv
  ushort* bufD = (ushort*)alloc((size_t)kNInv * 128 * 2);   // h_inv
  ushort* bufE = (ushort*)alloc((size_t)kNFund * 128 * 2);  // u_fund
  ushort* bufF = (ushort*)alloc((size_t)kNInv * 128 * 2);   // u_inv

  const int TB = 256;
  const int nbFund = (kNFund + 1023) / 1024;  // 20
  const int nbInv  = (kNInv + 1023) / 1024;   // 98
  const int gemmF = (kNFund + 127) / 128;     // 157
  const int gemmI = (kNInv + 127) / 128;      // 782

  // 1) fused prep: bf16 convert (64B/thread) + deg zero + composite weights
  prep<<<kPrepB + 17, 256, 0, stream>>>(
      x_inv, x_fund, W1l_if, W1r_if, W1l_fi, W1r_fi, xi_b, xf_b, wa,
      deg_fund, deg_inv,
      Wp1, W2l_fi, W2r_fi, W2l_if, W2r_if, b2_fi, b2_if, bp1, cw, bu_inv, bu_fund);

  // 2) count + rank capture (int4, 4 atomics/thread)
  const int n4 = kE / 4;  // 150000
  count_rank2<<<(2 * n4 + TB - 1) / TB, TB, 0, stream>>>(
      dst_if, deg_fund, rank_if, dst_fi, deg_inv, rank_fi, n4);

  // 3) scan (partial totals -> apply with inline bsum prefix)
  scan_partial2<<<nbFund + nbInv, 256, 0, stream>>>(deg_fund, bsumF, kNFund, nbFund,
                                                    deg_inv, bsumI, kNInv);
  scan_apply2<<<nbFund + nbInv, 256, 0, stream>>>(deg_fund, bsumF, off_fund, kNFund, nbFund,
                                                  deg_inv, bsumI, off_inv, kNInv);

  // 4) atomic-free fill
  fill2<<<(2 * kE + TB - 1) / TB, TB, 0, stream>>>(
      src_if, dst_if, rank_if, off_fund, csr_if,
      src_fi, dst_fi, rank_fi, off_inv, csr_fi, kE);

  const int meanBlocks = (kNFund + kNInv + 3) / 4;  // 30000

  // 5) layer 1: fund dst deg~30 -> DEP4; inv dst deg~6 -> DEP2
  sage_mean_dual<128, 4, 64, 2><<<meanBlocks, 256, 0, stream>>>(
      xi_b, csr_if, off_fund, bufA, kNFund, xf_b, csr_fi, off_inv, bufC, kNInv);
  gemm_stage1<<<gemmF + gemmI, 256, 0, stream>>>(
      bufA, xf_b, wa + kW1lIF, wa + kW1rIF, b1_if, bufB, kNFund, gemmF,
      bufC, xi_b, wa + kW1lFI, wa + kW1rFI, b1_fi, bufD, kNInv);
  // 6) layer 2 folded with predictor precompute
  sage_mean_dual<128, 4, 128, 2><<<meanBlocks, 256, 0, stream>>>(
      bufD, csr_if, off_fund, bufA, kNFund, bufB, csr_fi, off_inv, bufC, kNInv);
  gemm_stage2<<<gemmF + gemmI, 256, 0, stream>>>(
      bufA, bufB, cw + kCW2lIF, cw + kCW2rIF, bu_fund, bufE, kNFund, gemmF,
      bufC, bufD, cw + kCW2lFI, cw + kCW2rFI, bu_inv, bufF, kNInv);
  // 7) per-link
  link_pred<<<(kEL / 4 + 3) / 4, 256, 0, stream>>>(bufF, bufE, eli_inv, eli_fund,
                                                   Wp2, bp2, out, kEL);
}

// Round 14
// 296.890 us; speedup vs baseline: 1.0836x; 1.0083x over previous
//
#include <hip/hip_runtime.h>
#include <cstdint>
#include <cstddef>

namespace {

typedef short bf16x8 __attribute__((ext_vector_type(8)));
typedef float f32x4 __attribute__((ext_vector_type(4)));

constexpr int kNInv  = 100000;
constexpr int kNFund = 20000;
constexpr int kH     = 128;
constexpr int kE     = 600000;
constexpr int kEL    = 200000;

// L1 weight arena element offsets (bf16 elems)
constexpr int kW1lIF = 0;        // 128x128
constexpr int kW1rIF = 16384;    // 128x64
constexpr int kW1lFI = 24576;    // 128x64
constexpr int kW1rFI = 32768;    // 128x128
constexpr int kWTot  = 49152;

// composite (layer2 x predictor) arena: 4 x 128x128 bf16
constexpr int kCW2lFI = 0;
constexpr int kCW2rFI = 16384;
constexpr int kCW2lIF = 32768;
constexpr int kCW2rIF = 49152;

__device__ __forceinline__ float bf_lo(uint32_t u) {
  union { uint32_t i; float f; } v; v.i = u << 16; return v.f;
}
__device__ __forceinline__ float bf_hi(uint32_t u) {
  union { uint32_t i; float f; } v; v.i = u & 0xffff0000u; return v.f;
}
__device__ __forceinline__ ushort f2bf(float f) {  // round-nearest-even
  union { float f; uint32_t i; } v; v.f = f;
  uint32_t x = v.i;
  return (ushort)((x + 0x7fffu + ((x >> 16) & 1u)) >> 16);
}

// ---------- conversion / zero sizes (quad = float4/ushort4 of 4 elems) ----------
constexpr int kXiQ = kNInv * 128 / 4;            // 3,200,000 quads
constexpr int kXfQ = kNFund * 64 / 4;            // 320,000
constexpr int kWQ  = kWTot / 4;                  // 36,864
constexpr int kTotQ = kXiQ + kXfQ + kWQ;         // 3,556,864 (div by 4)
constexpr int kQT  = kTotQ / 4;                  // 889,216 convert threads (4 quads each)
constexpr int kZF4 = kNFund / 4;                 // 5,000 int4 zero chunks (fund)
constexpr int kZ4  = (kNFund + kNInv) / 16;      // 7,500 zero threads (4 int4 each)
constexpr int kPrepT = kQT + kZ4;
constexpr int kPrepB = (kPrepT + 255) / 256;

// ---------- f32 -> bf16 conversion, 4 quads (64B) per thread + deg zeroing ----------
__device__ void convert_body(int t, const float* __restrict__ xi, const float* __restrict__ xf,
                             const float* w0, const float* w1, const float* w2, const float* w3,
                             ushort* __restrict__ xi_b, ushort* __restrict__ xf_b,
                             ushort* __restrict__ wa,
                             int* __restrict__ deg_fund, int* __restrict__ deg_inv) {
  if (t >= kQT) {
    const int g = t - kQT;
    if (g >= kZ4) return;
    int z = g * 4;
#pragma unroll
    for (int j = 0; j < 4; ++j, ++z) {
      if (z < kZF4) ((int4*)deg_fund)[z] = make_int4(0, 0, 0, 0);
      else ((int4*)deg_inv)[z - kZF4] = make_int4(0, 0, 0, 0);
    }
    return;
  }
  const int q0 = t * 4;
  const float* src;
  ushort* dst;
  int sq, dq;  // quad indices
  if (q0 < kXiQ) {
    src = xi; dst = xi_b; sq = q0; dq = q0;
  } else if (q0 < kXiQ + kXfQ) {
    src = xf; dst = xf_b; sq = q0 - kXiQ; dq = sq;
  } else {
    const int e = (q0 - kXiQ - kXfQ) * 4;  // elem offset into arena
    const float* ws[4] = {w0, w1, w2, w3};
    const int beg[5] = {kW1lIF, kW1rIF, kW1lFI, kW1rFI, kWTot};
    int s = 0;
    while (e >= beg[s + 1]) ++s;
    src = ws[s]; dst = wa; sq = (e - beg[s]) / 4; dq = e / 4;
  }
#pragma unroll
  for (int j = 0; j < 4; ++j) {
    float4 v = ((const float4*)src)[sq + j];
    ushort4 o = make_ushort4(f2bf(v.x), f2bf(v.y), f2bf(v.z), f2bf(v.w));
    ((ushort4*)dst)[dq + j] = o;
  }
}

// ---------- composite weights: cW = Wp_half @ W2 (f32 math, bf16 out) ----------
__device__ void composite_body(int b, const float* __restrict__ Wp1,
                               const float* __restrict__ W2l_fi, const float* __restrict__ W2r_fi,
                               const float* __restrict__ W2l_if, const float* __restrict__ W2r_if,
                               const float* __restrict__ b2_fi, const float* __restrict__ b2_if,
                               const float* __restrict__ bp1,
                               ushort* __restrict__ cw, float* __restrict__ bu_inv,
                               float* __restrict__ bu_fund, float* sA /* [32*132] */) {
  const int tid = threadIdx.x;
  if (b == 16) {
    if (tid < 128) {
      float s = 0.f;
      for (int j = 0; j < 128; ++j) s += Wp1[(size_t)tid * 256 + j] * b2_fi[j];
      bu_inv[tid] = s;
    } else {
      const int o = tid - 128;
      float s = bp1[o];
      for (int j = 0; j < 128; ++j) s += Wp1[(size_t)o * 256 + 128 + j] * b2_if[j];
      bu_fund[o] = s;
    }
    return;
  }
  const int m = b >> 2;
  const int rb = (b & 3) * 32;
  const float* A = Wp1 + (m >= 2 ? 128 : 0);
  const float* B = (m == 0) ? W2l_fi : (m == 1) ? W2r_fi : (m == 2) ? W2l_if : W2r_if;
  for (int i = tid; i < 32 * 128; i += 256) {
    const int r = i >> 7, c = i & 127;
    sA[r * 132 + c] = A[(size_t)(rb + r) * 256 + c];
  }
  __syncthreads();
  const int lr = tid >> 3;
  const int k0 = (tid & 7) * 16;
  float acc[16];
#pragma unroll
  for (int i = 0; i < 16; ++i) acc[i] = 0.f;
  for (int j = 0; j < 128; ++j) {
    const float a = sA[lr * 132 + j];
    const float* Brow = B + (size_t)j * 128 + k0;
#pragma unroll
    for (int i = 0; i < 16; i += 4) {
      float4 v = *(const float4*)(Brow + i);
      acc[i] += a * v.x; acc[i + 1] += a * v.y; acc[i + 2] += a * v.z; acc[i + 3] += a * v.w;
    }
  }
  ushort* dst = cw + (size_t)m * 16384 + (size_t)(rb + lr) * 128 + k0;
  ushort ov[16];
#pragma unroll
  for (int i = 0; i < 16; ++i) ov[i] = f2bf(acc[i]);
#pragma unroll
  for (int i = 0; i < 16; i += 4)
    *(ushort4*)(dst + i) = *(const ushort4*)(ov + i);
}

// ---------- fused prep: [convert + deg-zero][composite] ----------
__global__ __launch_bounds__(256) void prep(
    const float* xi, const float* xf,
    const float* w0, const float* w1, const float* w2, const float* w3,
    ushort* xi_b, ushort* xf_b, ushort* wa,
    int* deg_fund, int* deg_inv,
    const float* Wp1, const float* W2l_fi, const float* W2r_fi,
    const float* W2l_if, const float* W2r_if,
    const float* b2_fi, const float* b2_if, const float* bp1,
    ushort* cw, float* bu_inv, float* bu_fund) {
  __shared__ float smem[32 * 132];
  const int b = blockIdx.x;
  if (b < kPrepB) {
    convert_body(b * 256 + threadIdx.x, xi, xf, w0, w1, w2, w3, xi_b, xf_b, wa,
                 deg_fund, deg_inv);
  } else {
    composite_body(b - kPrepB, Wp1, W2l_fi, W2r_fi, W2l_if, W2r_if,
                   b2_fi, b2_if, bp1, cw, bu_inv, bu_fund, smem);
  }
}

// ---------- count + rank capture: int4 dst loads, 4 atomics/thread ----------
__global__ void count_rank2(const int* __restrict__ d0, int* __restrict__ g0,
                            int* __restrict__ r0v,
                            const int* __restrict__ d1, int* __restrict__ g1,
                            int* __restrict__ r1v, int n4) {
  const int t = blockIdx.x * blockDim.x + threadIdx.x;
  if (t < n4) {
    int4 d = ((const int4*)d0)[t];
    const int e = t * 4;
    r0v[e]     = atomicAdd(&g0[d.x], 1);
    r0v[e + 1] = atomicAdd(&g0[d.y], 1);
    r0v[e + 2] = atomicAdd(&g0[d.z], 1);
    r0v[e + 3] = atomicAdd(&g0[d.w], 1);
  } else if (t < 2 * n4) {
    const int tt = t - n4;
    int4 d = ((const int4*)d1)[tt];
    const int e = tt * 4;
    r1v[e]     = atomicAdd(&g1[d.x], 1);
    r1v[e + 1] = atomicAdd(&g1[d.y], 1);
    r1v[e + 2] = atomicAdd(&g1[d.z], 1);
    r1v[e + 3] = atomicAdd(&g1[d.w], 1);
  }
}

// ---------- single-launch exclusive scan: each block self-computes its base ----------
// Block handles 1024 nodes; base = sum deg[0..blk*1024) read directly (int4, L2-hot).

__device__ void scan_fused_body(const int* __restrict__ deg, int* __restrict__ off,
                                int n, int blk) {
  __shared__ int red[256];
  __shared__ int sbase;
  const int tid = threadIdx.x;
  // base = sum of all preceding deg
  int part = 0;
  const int preq = (blk * 1024) / 4;  // int4 count (blk*1024 divisible by 4)
  const int4* d4 = (const int4*)deg;
  for (int i = tid; i < preq; i += 256) {
    int4 v = d4[i];
    part += v.x + v.y + v.z + v.w;
  }
  red[tid] = part;
  __syncthreads();
  for (int d = 128; d > 0; d >>= 1) {
    if (tid < d) red[tid] += red[tid + d];
    __syncthreads();
  }
  if (tid == 0) sbase = red[0];
  __syncthreads();
  const int base0 = sbase;

  const int base = blk * 1024 + tid * 4;
  int v[4] = {0, 0, 0, 0};
  const bool full = (base + 3 < n);
  if (full) {
    int4 t = *(const int4*)(deg + base);
    v[0] = t.x; v[1] = t.y; v[2] = t.z; v[3] = t.w;
  } else {
    for (int i = 0; i < 4; ++i)
      if (base + i < n) v[i] = deg[base + i];
  }
  const int s = v[0] + v[1] + v[2] + v[3];
  __syncthreads();
  red[tid] = s;
  __syncthreads();
  for (int d = 1; d < 256; d <<= 1) {
    int t = (tid >= d) ? red[tid - d] : 0;
    __syncthreads();
    red[tid] += t;
    __syncthreads();
  }
  int o[4];
  o[0] = base0 + red[tid] - s;
  o[1] = o[0] + v[0];
  o[2] = o[1] + v[1];
  o[3] = o[2] + v[2];
  if (full) {
    *(int4*)(off + base) = make_int4(o[0], o[1], o[2], o[3]);
  } else {
    for (int i = 0; i < 4; ++i)
      if (base + i < n) off[base + i] = o[i];
  }
#pragma unroll
  for (int i = 0; i < 4; ++i)
    if (base + i == n - 1) off[n] = o[i] + v[i];
}

__global__ void scan_fused2(const int* __restrict__ degF, int* __restrict__ offF, int nF, int nbF,
                            const int* __restrict__ degI, int* __restrict__ offI, int nI) {
  if ((int)blockIdx.x < nbF) scan_fused_body(degF, offF, nF, blockIdx.x);
  else scan_fused_body(degI, offI, nI, blockIdx.x - nbF);
}

// ---------- atomic-free CSR fill using captured ranks (4 edges/thread) ----------
__global__ void fill2(const int* __restrict__ s0, const int* __restrict__ d0,
                      const int* __restrict__ r0v, const int* __restrict__ off0,
                      int* __restrict__ c0,
                      const int* __restrict__ s1, const int* __restrict__ d1,
                      const int* __restrict__ r1v, const int* __restrict__ off1,
                      int* __restrict__ c1, int n4) {
  const int t = blockIdx.x * blockDim.x + threadIdx.x;
  if (t < n4) {
    int4 d = ((const int4*)d0)[t];
    int4 r = ((const int4*)r0v)[t];
    int4 s = ((const int4*)s0)[t];
    c0[off0[d.x] + r.x] = s.x;
    c0[off0[d.y] + r.y] = s.y;
    c0[off0[d.z] + r.z] = s.z;
    c0[off0[d.w] + r.w] = s.w;
  } else if (t < 2 * n4) {
    const int tt = t - n4;
    int4 d = ((const int4*)d1)[tt];
    int4 r = ((const int4*)r1v)[tt];
    int4 s = ((const int4*)s1)[tt];
    c1[off1[d.x] + r.x] = s.x;
    c1[off1[d.y] + r.y] = s.y;
    c1[off1[d.z] + r.z] = s.z;
    c1[off1[d.w] + r.w] = s.w;
  }
}

// ---------- mean aggregation: clamped 4/2-deep, subgroup decomposition ----------

__device__ __forceinline__ void acc8w(float* a, uint4 u, float w) {
  a[0] = fmaf(w, bf_lo(u.x), a[0]); a[1] = fmaf(w, bf_hi(u.x), a[1]);
  a[2] = fmaf(w, bf_lo(u.y), a[2]); a[3] = fmaf(w, bf_hi(u.y), a[3]);
  a[4] = fmaf(w, bf_lo(u.z), a[4]); a[5] = fmaf(w, bf_hi(u.z), a[5]);
  a[6] = fmaf(w, bf_lo(u.w), a[6]); a[7] = fmaf(w, bf_hi(u.w), a[7]);
}

template <int D, int DEP>
__device__ __forceinline__ void mean_node(const ushort* __restrict__ xsrc,
                                          const int* __restrict__ csr,
                                          const int* __restrict__ off,
                                          ushort* __restrict__ mean, int node, int lane) {
  constexpr int NSUB = (D == 128) ? 4 : 8;
  const int sub = (D == 128) ? (lane >> 4) : (lane >> 3);
  const int ll  = (D == 128) ? (lane & 15) : (lane & 7);
  const size_t co = (size_t)ll * 8;
  const int lo = off[node], hi = off[node + 1];
  float a[8] = {0.f, 0.f, 0.f, 0.f, 0.f, 0.f, 0.f, 0.f};
  for (int e0 = lo + sub; e0 < hi; e0 += NSUB * DEP) {
    int idx[DEP];
    float w[DEP];
#pragma unroll
    for (int j = 0; j < DEP; ++j) {
      const int e = e0 + NSUB * j;
      idx[j] = csr[min(e, hi - 1)];
      w[j] = (e < hi) ? 1.0f : 0.0f;
    }
    uint4 u[DEP];
#pragma unroll
    for (int j = 0; j < DEP; ++j)
      u[j] = *(const uint4*)(xsrc + (size_t)idx[j] * D + co);
#pragma unroll
    for (int j = 0; j < DEP; ++j) acc8w(a, u[j], w[j]);
  }
#pragma unroll
  for (int i = 0; i < 8; ++i) {
    if (D == 64) a[i] += __shfl_xor(a[i], 8);
    a[i] += __shfl_xor(a[i], 16);
    a[i] += __shfl_xor(a[i], 32);
  }
  if (sub == 0) {
    const float sc = (hi > lo) ? 1.0f / (float)(hi - lo) : 0.0f;
    ushort o8[8];
#pragma unroll
    for (int i = 0; i < 8; ++i) o8[i] = f2bf(a[i] * sc);
    *(uint4*)(mean + (size_t)node * D + co) = *(const uint4*)o8;
  }
}

template <int DA, int DEPA, int DB, int DEPB>
__global__ void sage_mean_dual(const ushort* __restrict__ xA, const int* __restrict__ csrA,
                               const int* __restrict__ offA, ushort* __restrict__ outA, int nA,
                               const ushort* __restrict__ xB, const int* __restrict__ csrB,
                               const int* __restrict__ offB, ushort* __restrict__ outB, int nB) {
  const int wave = (int)((blockIdx.x * blockDim.x + threadIdx.x) >> 6);
  const int lane = threadIdx.x & 63;
  if (wave < nA) mean_node<DA, DEPA>(xA, csrA, offA, outA, wave, lane);
  else if (wave < nA + nB) mean_node<DB, DEPB>(xB, csrB, offB, outB, wave - nA, lane);
}

// ---------- MFMA GEMM body: 512 threads, 256 rows per block ----------
// W staged once to LDS (fragment-major, conflict-free); A fragments hoisted.
// 512 threads -> 8 waves share the W tile: 2 blocks/CU -> ~16 waves/CU.

template <int D1, int D2>
__device__ void gemm_body(const ushort* __restrict__ A1, const ushort* __restrict__ A2,
                          const ushort* __restrict__ W1, const ushort* __restrict__ W2,
                          const float* __restrict__ bias, int act,
                          ushort* __restrict__ out, int n, int blk, ushort* lds) {
  constexpr int K1 = D1 / 32;
  constexpr int K2 = D2 / 32;
  constexpr int CH1 = 128 * D1 / 8;
  constexpr int CHT = 128 * (D1 + D2) / 8;

  const int tid = threadIdx.x;
  const int wid = tid >> 6;
  const int lane = tid & 63;
  const int lo16 = lane & 15;
  const int hi4 = lane >> 4;
  const int row0 = blk * 256 + wid * 32;

  const int r0 = min(row0 + lo16, n - 1);
  const int r1 = min(row0 + 16 + lo16, n - 1);

  bf16x8 aA[2][K1], aB[2][K2];
  {
    const ushort* a0p = A1 + (size_t)r0 * D1 + hi4 * 8;
    const ushort* a1p = A1 + (size_t)r1 * D1 + hi4 * 8;
#pragma unroll
    for (int k = 0; k < K1; ++k) {
      aA[0][k] = *(const bf16x8*)(a0p + k * 32);
      aA[1][k] = *(const bf16x8*)(a1p + k * 32);
    }
    const ushort* b0p = A2 + (size_t)r0 * D2 + hi4 * 8;
    const ushort* b1p = A2 + (size_t)r1 * D2 + hi4 * 8;
#pragma unroll
    for (int k = 0; k < K2; ++k) {
      aB[0][k] = *(const bf16x8*)(b0p + k * 32);
      aB[1][k] = *(const bf16x8*)(b1p + k * 32);
    }
  }

#pragma unroll
  for (int it = 0; it < CHT / 512; ++it) {
    const int c = it * 512 + tid;
    const int g = c * 8;
    bf16x8 v;
    int dest;
    if (g < 128 * D1) {
      const int row = g / D1, col = g % D1;
      v = *(const bf16x8*)(W1 + g);
      dest = ((col >> 5) * 8 + (row >> 4)) * 64 + (((col >> 3) & 3) << 4) + (row & 15);
    } else {
      const int g2 = g - 128 * D1;
      const int row = g2 / D2, col = g2 % D2;
      v = *(const bf16x8*)(W2 + g2);
      dest = CH1 + ((col >> 5) * 8 + (row >> 4)) * 64 + (((col >> 3) & 3) << 4) + (row & 15);
    }
    *((bf16x8*)lds + dest) = v;
  }
  __syncthreads();

  f32x4 acc[2][8];
#pragma unroll
  for (int rt = 0; rt < 2; ++rt)
#pragma unroll
    for (int ct = 0; ct < 8; ++ct)
      acc[rt][ct] = (f32x4){0.f, 0.f, 0.f, 0.f};

  const bf16x8* fr = (const bf16x8*)lds;
#pragma unroll
  for (int k = 0; k < K1; ++k) {
#pragma unroll
    for (int ct = 0; ct < 8; ++ct) {
      bf16x8 w = fr[(k * 8 + ct) * 64 + lane];
      acc[0][ct] = __builtin_amdgcn_mfma_f32_16x16x32_bf16(w, aA[0][k], acc[0][ct], 0, 0, 0);
      acc[1][ct] = __builtin_amdgcn_mfma_f32_16x16x32_bf16(w, aA[1][k], acc[1][ct], 0, 0, 0);
    }
  }
#pragma unroll
  for (int k = 0; k < K2; ++k) {
#pragma unroll
    for (int ct = 0; ct < 8; ++ct) {
      bf16x8 w = fr[CH1 + (k * 8 + ct) * 64 + lane];
      acc[0][ct] = __builtin_amdgcn_mfma_f32_16x16x32_bf16(w, aB[0][k], acc[0][ct], 0, 0, 0);
      acc[1][ct] = __builtin_amdgcn_mfma_f32_16x16x32_bf16(w, aB[1][k], acc[1][ct], 0, 0, 0);
    }
  }

  const int colb = hi4 * 4;
#pragma unroll
  for (int rt = 0; rt < 2; ++rt) {
    const int row = row0 + rt * 16 + lo16;
    if (row < n) {
#pragma unroll
      for (int ct = 0; ct < 8; ++ct) {
        float b4[4];
        *(float4*)b4 = *(const float4*)(bias + ct * 16 + colb);
        ushort o[4];
#pragma unroll
        for (int j = 0; j < 4; ++j) {
          float x = acc[rt][ct][j] + b4[j];
          if (act) x = fmaxf(x, 0.f);
          o[j] = f2bf(x);
        }
        *(ushort4*)(out + (size_t)row * kH + ct * 16 + colb) = *(const ushort4*)o;
      }
    }
  }
}

__global__ __launch_bounds__(512) void gemm_stage1(
    const ushort* A1f, const ushort* A2f, const ushort* W1f, const ushort* W2f,
    const float* biasf, ushort* outf, int nf, int nbf,
    const ushort* A1i, const ushort* A2i, const ushort* W1i, const ushort* W2i,
    const float* biasi, ushort* outi, int ni) {
  __shared__ ushort lds[128 * 192];
  if ((int)blockIdx.x < nbf)
    gemm_body<128, 64>(A1f, A2f, W1f, W2f, biasf, 1, outf, nf, blockIdx.x, lds);
  else
    gemm_body<64, 128>(A1i, A2i, W1i, W2i, biasi, 1, outi, ni, blockIdx.x - nbf, lds);
}

__global__ __launch_bounds__(512) void gemm_stage2(
    const ushort* A1f, const ushort* A2f, const ushort* W1f, const ushort* W2f,
    const float* biasf, ushort* outf, int nf, int nbf,
    const ushort* A1i, const ushort* A2i, const ushort* W1i, const ushort* W2i,
    const float* biasi, ushort* outi, int ni) {
  __shared__ ushort lds[128 * 256];
  if ((int)blockIdx.x < nbf)
    gemm_body<128, 128>(A1f, A2f, W1f, W2f, biasf, 0, outf, nf, blockIdx.x, lds);
  else
    gemm_body<128, 128>(A1i, A2i, W1i, W2i, biasi, 0, outi, ni, blockIdx.x - nbf, lds);
}

// ---------- link predictor: 4 links per wave (16-lane quads, 16B/lane) ----------

__global__ void link_pred(const ushort* __restrict__ u_inv, const ushort* __restrict__ u_fund,
                          const int* __restrict__ ei, const int* __restrict__ ej,
                          const float* __restrict__ Wp2, const float* __restrict__ bp2,
                          float* __restrict__ out, int nl) {
  const int wave = (int)((blockIdx.x * blockDim.x + threadIdx.x) >> 6);
  const int lane = threadIdx.x & 63;
  const int q = lane >> 4, l16 = lane & 15;
  const int link = wave * 4 + q;
  if (link >= nl) return;
  const int i = ei[link];
  const int j = ej[link];
  uint4 ua = *(const uint4*)(u_inv + (size_t)i * 128 + l16 * 8);
  uint4 ub = *(const uint4*)(u_fund + (size_t)j * 128 + l16 * 8);
  float4 w0 = *(const float4*)(Wp2 + l16 * 8);
  float4 w1 = *(const float4*)(Wp2 + l16 * 8 + 4);
  float p = fmaxf(bf_lo(ua.x) + bf_lo(ub.x), 0.f) * w0.x
          + fmaxf(bf_hi(ua.x) + bf_hi(ub.x), 0.f) * w0.y
          + fmaxf(bf_lo(ua.y) + bf_lo(ub.y), 0.f) * w0.z
          + fmaxf(bf_hi(ua.y) + bf_hi(ub.y), 0.f) * w0.w
          + fmaxf(bf_lo(ua.z) + bf_lo(ub.z), 0.f) * w1.x
          + fmaxf(bf_hi(ua.z) + bf_hi(ub.z), 0.f) * w1.y
          + fmaxf(bf_lo(ua.w) + bf_lo(ub.w), 0.f) * w1.z
          + fmaxf(bf_hi(ua.w) + bf_hi(ub.w), 0.f) * w1.w;
#pragma unroll
  for (int o = 8; o > 0; o >>= 1) p += __shfl_xor(p, o);
  if (l16 == 0) out[link] = 1.0f / (1.0f + expf(-(p + bp2[0])));
}

}  // namespace

extern "C" void kernel_launch(void* const* d_in, const int* in_sizes, int n_in,
                              void* d_out, int out_size, void* d_ws, size_t ws_size,
                              hipStream_t stream) {
  const float* x_inv  = (const float*)d_in[0];
  const float* x_fund = (const float*)d_in[1];
  const int* src_if   = (const int*)d_in[2];
  const int* dst_if   = (const int*)d_in[3];
  const int* src_fi   = (const int*)d_in[4];
  const int* dst_fi   = (const int*)d_in[5];
  const int* eli_inv  = (const int*)d_in[6];
  const int* eli_fund = (const int*)d_in[7];
  const float* W1l_if = (const float*)d_in[8];
  const float* b1_if  = (const float*)d_in[9];
  const float* W1r_if = (const float*)d_in[10];
  const float* W1l_fi = (const float*)d_in[11];
  const float* b1_fi  = (const float*)d_in[12];
  const float* W1r_fi = (const float*)d_in[13];
  const float* W2l_if = (const float*)d_in[14];
  const float* b2_if  = (const float*)d_in[15];
  const float* W2r_if = (const float*)d_in[16];
  const float* W2l_fi = (const float*)d_in[17];
  const float* b2_fi  = (const float*)d_in[18];
  const float* W2r_fi = (const float*)d_in[19];
  const float* Wp1    = (const float*)d_in[20];
  const float* bp1    = (const float*)d_in[21];
  const float* Wp2    = (const float*)d_in[22];
  const float* bp2    = (const float*)d_in[23];
  float* out = (float*)d_out;

  char* p = (char*)d_ws;
  auto alloc = [&](size_t bytes) -> void* {
    void* r = (void*)p;
    p += (bytes + 255) & ~(size_t)255;
    return r;
  };
  int* deg_fund = (int*)alloc((size_t)kNFund * 4);
  int* deg_inv  = (int*)alloc((size_t)kNInv * 4);
  int* off_fund = (int*)alloc((size_t)(kNFund + 1) * 4);
  int* off_inv  = (int*)alloc((size_t)(kNInv + 1) * 4);
  int* rank_if  = (int*)alloc((size_t)kE * 4);
  int* rank_fi  = (int*)alloc((size_t)kE * 4);
  int* csr_if   = (int*)alloc((size_t)kE * 4);
  int* csr_fi   = (int*)alloc((size_t)kE * 4);
  ushort* xi_b = (ushort*)alloc((size_t)kNInv * 128 * 2);
  ushort* xf_b = (ushort*)alloc((size_t)kNFund * 64 * 2);
  ushort* wa   = (ushort*)alloc((size_t)kWTot * 2);
  ushort* cw   = (ushort*)alloc((size_t)4 * 16384 * 2);
  float* bu_inv  = (float*)alloc((size_t)128 * 4);
  float* bu_fund = (float*)alloc((size_t)128 * 4);
  ushort* bufA = (ushort*)alloc((size_t)kNFund * 128 * 2);  // mean_fund
  ushort* bufB = (ushort*)alloc((size_t)kNFund * 128 * 2);  // h_fund
  ushort* bufC = (ushort*)alloc((size_t)kNInv * 128 * 2);   // mean_inv
  ushort* bufD = (ushort*)alloc((size_t)kNInv * 128 * 2);   // h_inv
  ushort* bufE = (ushort*)alloc((size_t)kNFund * 128 * 2);  // u_fund
  ushort* bufF = (ushort*)alloc((size_t)kNInv * 128 * 2);   // u_inv

  const int TB = 256;
  const int nbFund = (kNFund + 1023) / 1024;  // 20
  const int nbInv  = (kNInv + 1023) / 1024;   // 98
  const int gemmF = (kNFund + 255) / 256;     // 79
  const int gemmI = (kNInv + 255) / 256;      // 391

  // 1) fused prep: bf16 convert (64B/thread) + deg zero + composite weights
  prep<<<kPrepB + 17, 256, 0, stream>>>(
      x_inv, x_fund, W1l_if, W1r_if, W1l_fi, W1r_fi, xi_b, xf_b, wa,
      deg_fund, deg_inv,
      Wp1, W2l_fi, W2r_fi, W2l_if, W2r_if, b2_fi, b2_if, bp1, cw, bu_inv, bu_fund);

  // 2) count + rank capture (int4, 4 atomics/thread) — at atomic-fabric ceiling
  const int n4 = kE / 4;  // 150000
  count_rank2<<<(2 * n4 + TB - 1) / TB, TB, 0, stream>>>(
      dst_if, deg_fund, rank_if, dst_fi, deg_inv, rank_fi, n4);

  // 3) single-launch scan (each block self-computes its base from deg directly)
  scan_fused2<<<nbFund + nbInv, 256, 0, stream>>>(deg_fund, off_fund, kNFund, nbFund,
                                                  deg_inv, off_inv, kNInv);

  // 4) atomic-free fill (4 edges/thread)
  fill2<<<(2 * n4 + TB - 1) / TB, TB, 0, stream>>>(
      src_if, dst_if, rank_if, off_fund, csr_if,
      src_fi, dst_fi, rank_fi, off_inv, csr_fi, n4);

  const int meanBlocks = (kNFund + kNInv + 3) / 4;  // 30000

  // 5) layer 1: fund dst deg~30 -> DEP4; inv dst deg~6 -> DEP2
  sage_mean_dual<128, 4, 64, 2><<<meanBlocks, 256, 0, stream>>>(
      xi_b, csr_if, off_fund, bufA, kNFund, xf_b, csr_fi, off_inv, bufC, kNInv);
  gemm_stage1<<<gemmF + gemmI, 512, 0, stream>>>(
      bufA, xf_b, wa + kW1lIF, wa + kW1rIF, b1_if, bufB, kNFund, gemmF,
      bufC, xi_b, wa + kW1lFI, wa + kW1rFI, b1_fi, bufD, kNInv);
  // 6) layer 2 folded with predictor precompute
  sage_mean_dual<128, 4, 128, 2><<<meanBlocks, 256, 0, stream>>>(
      bufD, csr_if, off_fund, bufA, kNFund, bufB, csr_fi, off_inv, bufC, kNInv);
  gemm_stage2<<<gemmF + gemmI, 512, 0, stream>>>(
      bufA, bufB, cw + kCW2lIF, cw + kCW2rIF, bu_fund, bufE, kNFund, gemmF,
      bufC, bufD, cw + kCW2lFI, cw + kCW2rFI, bu_inv, bufF, kNInv);
  // 7) per-link
  link_pred<<<(kEL / 4 + 3) / 4, 256, 0, stream>>>(bufF, bufE, eli_inv, eli_fund,
                                                   Wp2, bp2, out, kEL);
}